// Round 2
// 5299.992 us; speedup vs baseline: 4.3931x; 4.3931x over previous
//
#include <hip/hip_runtime.h>
#include <hip/hip_bf16.h>
#include <math.h>

#define B_    512
#define T_    128
#define DET_  512
#define STOCH_ 32
#define EMB_  1024
#define ACTD_ 6
#define HID_  512

// output slice offsets (floats)
#define OFF_STOCH 33554432u
#define OFF_PM    35651584u
#define OFF_PS    37748736u
#define OFF_QM    39845888u
#define OFF_QS    41943040u

typedef short bhalf8 __attribute__((ext_vector_type(8)));
typedef float f32x4  __attribute__((ext_vector_type(4)));

__device__ __forceinline__ float sigm(float x) { return 1.f / (1.f + __expf(-x)); }
__device__ __forceinline__ float softplusf(float x) {
    return fmaxf(x, 0.f) + log1pf(__expf(-fabsf(x)));
}
__device__ __forceinline__ float eluf(float x) { return (x > 0.f) ? x : (__expf(x) - 1.f); }
__device__ __forceinline__ float tanh_fast(float x) {
    return 1.f - 2.f / (__expf(2.f * x) + 1.f);
}
__device__ __forceinline__ short f2bf(float f) {
    __hip_bfloat16 h = __float2bfloat16(f);
    return *reinterpret_cast<short*>(&h);
}
__device__ __forceinline__ void pack4(short* dst, float4 f) {
    dst[0] = f2bf(f.x); dst[1] = f2bf(f.y); dst[2] = f2bf(f.z); dst[3] = f2bf(f.w);
}

// Packed-B addressing: weight W[N][K] stored as (N/16)x(K/32) blocks of 512
// shorts; within a block lane L holds W[n = bn*16 + (L&15)][k = bk*32 + (L>>4)*8 + j]
// at short offset L*8+j  ->  a wave's B-fragment load is 1024 CONTIGUOUS bytes.
__device__ __forceinline__ const bhalf8* pb(const short* base, int KT, int bn, int bk, int lane) {
    return (const bhalf8*)(base + ((size_t)((bn * KT + bk) * 64 + lane) << 3));
}

// ---------------------------------------------------------------------------
// Prep: bf16 weight images (fragment-packed) in the ps output slice.
//   WBIGp: N=2048,K=576 (bn 0..127, KT=18). N-rows: 0..511 r [wih_r|whh_r],
//     512..1023 z, 1024..1535 hn [0|whh_n], 1536..2047 xn [wih_n|0].
//     K: k<64 = [s(32),a(6),0(26)], k>=64 = h.
//   RW1s: rep_w1 h-part  N=512,K=512  (KT=16)
//   RW1e: rep_w1 e-part  N=512,K=1024 (KT=32)
//   RW2p: rep_w2         N=64, K=512  (KT=16)
// ---------------------------------------------------------------------------
__global__ __launch_bounds__(256) void k_prep(
    const float* __restrict__ wih, const float* __restrict__ whh,
    const float* __restrict__ rw1, const float* __restrict__ rw2,
    short* __restrict__ WBIGp, short* __restrict__ RW1s,
    short* __restrict__ RW1e, short* __restrict__ RW2p)
{
    const int idx = blockIdx.x * 256 + threadIdx.x;
    const int stride = gridDim.x * 256;

    for (int i = idx; i < 128 * 18 * 512; i += stride) {
        int blk = i >> 9, r = i & 511;
        int lane = r >> 3, j = r & 7;
        int bn = blk / 18, bk = blk - bn * 18;
        int n = bn * 16 + (lane & 15);
        int k = bk * 32 + (lane >> 4) * 8 + j;
        float v = 0.f;
        if (k < 64) {
            if (k < 38) {
                if (n < 1024)       v = wih[n * 38 + k];
                else if (n >= 1536) v = wih[(n - 512) * 38 + k];
            }
        } else {
            if (n < 1536) v = whh[(size_t)n * 512 + (k - 64)];
        }
        WBIGp[i] = f2bf(v);
    }
    for (int i = idx; i < 32 * 16 * 512; i += stride) {
        int blk = i >> 9, r = i & 511;
        int lane = r >> 3, j = r & 7;
        int bn = blk >> 4, bk = blk & 15;
        int n = bn * 16 + (lane & 15), k = bk * 32 + (lane >> 4) * 8 + j;
        RW1s[i] = f2bf(rw1[(size_t)n * 1536 + k]);
    }
    for (int i = idx; i < 32 * 32 * 512; i += stride) {
        int blk = i >> 9, r = i & 511;
        int lane = r >> 3, j = r & 7;
        int bn = blk >> 5, bk = blk & 31;
        int n = bn * 16 + (lane & 15), k = bk * 32 + (lane >> 4) * 8 + j;
        RW1e[i] = f2bf(rw1[(size_t)n * 1536 + 512 + k]);
    }
    for (int i = idx; i < 4 * 16 * 512; i += stride) {
        int blk = i >> 9, r = i & 511;
        int lane = r >> 3, j = r & 7;
        int bn = blk >> 4, bk = blk & 15;
        int n = bn * 16 + (lane & 15), k = bk * 32 + (lane >> 4) * 8 + j;
        RW2p[i] = f2bf(rw2[n * 512 + k]);
    }
}

// ---------------------------------------------------------------------------
// E1 precompute: E1[b,t,:] = emb[b,t,:] @ RW1e^T + rb1   (the scan-independent
// 2/3 of the rep1 K-reduction, + its bias). Stored fp32 into the det slice
// ([b][t][512] layout); k_scan reads E1[b,t] at step t then overwrites with h.
// Fully parallel: grid 1024, M=64 rows/WG, K=1024, N=512 (4 waves x 128).
// ---------------------------------------------------------------------------
__global__ __launch_bounds__(256) void k_e1(
    const float* __restrict__ emb, const short* __restrict__ RW1e,
    const float* __restrict__ rb1, float* __restrict__ e1out)
{
    __shared__ __align__(16) short A[64][1032];
    const int tid = threadIdx.x;
    const int lane = tid & 63, w = tid >> 6;
    const int q = lane >> 4, m16 = lane & 15;
    const size_t row0 = (size_t)blockIdx.x * 64;

    // stage 64 rows x 1024 fp32 -> bf16 (4 thr/row x 256 cols)
    {
        const int row = tid >> 2, c0 = (tid & 3) * 256;
        const float* src = emb + (row0 + row) * EMB_ + c0;
        #pragma unroll
        for (int v = 0; v < 16; ++v) {
            float4 f0 = ((const float4*)src)[v * 4 + 0];
            float4 f1 = ((const float4*)src)[v * 4 + 1];
            float4 f2 = ((const float4*)src)[v * 4 + 2];
            float4 f3 = ((const float4*)src)[v * 4 + 3];
            short tmp[16] __attribute__((aligned(16)));
            pack4(&tmp[0], f0); pack4(&tmp[4], f1);
            pack4(&tmp[8], f2); pack4(&tmp[12], f3);
            *(bhalf8*)&A[row][c0 + v * 16]     = *(bhalf8*)&tmp[0];
            *(bhalf8*)&A[row][c0 + v * 16 + 8] = *(bhalf8*)&tmp[8];
        }
    }
    __syncthreads();

    float rb1g[8];
    #pragma unroll
    for (int ti = 0; ti < 8; ++ti) rb1g[ti] = rb1[w * 128 + ti * 16 + m16];

    f32x4 acc[4][8];
    #pragma unroll
    for (int mt = 0; mt < 4; ++mt)
        #pragma unroll
        for (int ti = 0; ti < 8; ++ti) acc[mt][ti] = (f32x4){0.f, 0.f, 0.f, 0.f};

    #pragma unroll 2
    for (int kt = 0; kt < 32; ++kt) {
        const int k0 = kt * 32;
        bhalf8 af[4];
        #pragma unroll
        for (int mt = 0; mt < 4; ++mt)
            af[mt] = *(const bhalf8*)&A[mt * 16 + m16][k0 + q * 8];
        #pragma unroll
        for (int ti = 0; ti < 8; ++ti) {
            bhalf8 bv = *pb(RW1e, 32, w * 8 + ti, kt, lane);
            #pragma unroll
            for (int mt = 0; mt < 4; ++mt)
                acc[mt][ti] = __builtin_amdgcn_mfma_f32_16x16x32_bf16(af[mt], bv, acc[mt][ti], 0, 0, 0);
        }
    }
    #pragma unroll
    for (int mt = 0; mt < 4; ++mt)
        #pragma unroll
        for (int ti = 0; ti < 8; ++ti) {
            const int j = w * 128 + ti * 16 + m16;
            #pragma unroll
            for (int rr = 0; rr < 4; ++rr)
                e1out[(row0 + mt * 16 + q * 4 + rr) * DET_ + j] = acc[mt][ti][rr] + rb1g[ti];
        }
}

// ---------------------------------------------------------------------------
// Persistent scan: 32 WGs x 512 thr (8 waves -> 2 waves/SIMD for latency
// hiding); WG owns 16 batch rows for all 128 steps. Wave w owns N-cols
// [w*64, w*64+64) of GRU gates and rep1. All weight loads are fragment-packed
// 1-KB coalesced bursts. rep1 K=512 (h-part only); its accumulator is
// initialized from the precomputed E1 (read from det slice, which is then
// overwritten with h AFTER rep1's MFMAs have consumed the E1 loads).
// ---------------------------------------------------------------------------
__global__ __launch_bounds__(512, 2) void k_scan(
    const float* __restrict__ actions, const float* __restrict__ noise,
    const short* __restrict__ WBIGp, const short* __restrict__ RW1s,
    const short* __restrict__ RW2p,
    const float* __restrict__ bih, const float* __restrict__ bhh,
    const float* __restrict__ rb2,
    float* __restrict__ det, float* __restrict__ stoch,
    float* __restrict__ qm, float* __restrict__ qsd)
{
    __shared__ __align__(16) short gruA[16][584];   // [s|a|pad|h] bf16
    __shared__ __align__(16) short repA[16][520];   // h bf16
    __shared__ __align__(16) short q1A[16][520];    // q1 bf16
    __shared__ float o2[16][68];                    // rep2 out fp32

    const int tid = threadIdx.x;
    const int lane = tid & 63, w = tid >> 6;
    const int q = lane >> 4, m16 = lane & 15;
    const int b0 = blockIdx.x * 16;
    const f32x4 zero4 = {0.f, 0.f, 0.f, 0.f};

    // ---- prologue ----
    for (int i = tid; i < 16 * 584; i += 512) ((short*)gruA)[i] = 0;
    if (tid < 96) {
        int row = tid / 6, k = tid - row * 6;
        gruA[row][32 + k] = f2bf(actions[((size_t)(b0 + row) * T_) * ACTD_ + k]);
    }
    float brg[4], bzg[4], bnxg[4], bnhg[4];
    #pragma unroll
    for (int ti = 0; ti < 4; ++ti) {
        int j = w * 64 + ti * 16 + m16;
        brg[ti]  = bih[j] + bhh[j];
        bzg[ti]  = bih[512 + j] + bhh[512 + j];
        bnxg[ti] = bih[1024 + j];
        bnhg[ti] = bhh[1024 + j];
    }
    const float rb2g = (w < 4) ? rb2[w * 16 + m16] : 0.f;
    float hprev[4][4];
    #pragma unroll
    for (int ti = 0; ti < 4; ++ti)
        #pragma unroll
        for (int rr = 0; rr < 4; ++rr) hprev[ti][rr] = 0.f;
    __syncthreads();

    for (int t = 0; t < T_; ++t) {
        // ---- E1 prefetch: rep1 accumulator init, issued early; latency
        // hides under the GRU GEMM. Reads det[b][t] BEFORE this step's h
        // overwrites it (stores are placed after rep1's MFMAs; vmcnt FIFO
        // guarantees these older loads drain before any such store issues).
        f32x4 a1[4];
        #pragma unroll
        for (int ti = 0; ti < 4; ++ti) {
            const int j = w * 64 + ti * 16 + m16;
            #pragma unroll
            for (int rr = 0; rr < 4; ++rr)
                a1[ti][rr] = det[((size_t)(b0 + q * 4 + rr) * T_ + t) * DET_ + j];
        }

        // ---- GRU GEMM (gruA x WBIGp), K=576 ----
        f32x4 aR[4], aZ[4], aN[4], aX[4];
        #pragma unroll
        for (int ti = 0; ti < 4; ++ti) { aR[ti] = zero4; aZ[ti] = zero4; aN[ti] = zero4; aX[ti] = zero4; }

        #pragma unroll 2
        for (int kt = 0; kt < 18; ++kt) {
            const int k0 = kt * 32;
            bhalf8 af = *(const bhalf8*)&gruA[m16][k0 + q * 8];
            #pragma unroll
            for (int ti = 0; ti < 4; ++ti) {
                const int bn = w * 4 + ti;
                bhalf8 bR = *pb(WBIGp, 18, bn, kt, lane);
                bhalf8 bZ = *pb(WBIGp, 18, 32 + bn, kt, lane);
                if (kt < 2) {
                    bhalf8 bX = *pb(WBIGp, 18, 96 + bn, kt, lane);   // xn (x-part)
                    aX[ti] = __builtin_amdgcn_mfma_f32_16x16x32_bf16(af, bX, aX[ti], 0, 0, 0);
                } else {
                    bhalf8 bN = *pb(WBIGp, 18, 64 + bn, kt, lane);   // hn (h-part)
                    aN[ti] = __builtin_amdgcn_mfma_f32_16x16x32_bf16(af, bN, aN[ti], 0, 0, 0);
                }
                aR[ti] = __builtin_amdgcn_mfma_f32_16x16x32_bf16(af, bR, aR[ti], 0, 0, 0);
                aZ[ti] = __builtin_amdgcn_mfma_f32_16x16x32_bf16(af, bZ, aZ[ti], 0, 0, 0);
            }
        }

        // ---- gate epilogue: h in regs; repA now, gruA h after barrier ----
        #pragma unroll
        for (int ti = 0; ti < 4; ++ti) {
            const int j = w * 64 + ti * 16 + m16;
            #pragma unroll
            for (int rr = 0; rr < 4; ++rr) {
                float r = sigm(aR[ti][rr] + brg[ti]);
                float z = sigm(aZ[ti][rr] + bzg[ti]);
                float n = tanh_fast(aX[ti][rr] + bnxg[ti] + r * (aN[ti][rr] + bnhg[ti]));
                float h = (1.f - z) * n + z * hprev[ti][rr];
                hprev[ti][rr] = h;
                repA[q * 4 + rr][j] = f2bf(h);
            }
        }
        __syncthreads();   // (1) all GRU reads of gruA done; repA h complete
        #pragma unroll
        for (int ti = 0; ti < 4; ++ti) {
            const int j = w * 64 + ti * 16 + m16;
            #pragma unroll
            for (int rr = 0; rr < 4; ++rr)
                gruA[q * 4 + rr][64 + j] = f2bf(hprev[ti][rr]);
        }

        // ---- rep1 GEMM (repA x RW1s), K=512, acc pre-seeded with E1+rb1 ----
        #pragma unroll 2
        for (int kt = 0; kt < 16; ++kt) {
            const int k0 = kt * 32;
            bhalf8 af = *(const bhalf8*)&repA[m16][k0 + q * 8];
            #pragma unroll
            for (int ti = 0; ti < 4; ++ti) {
                bhalf8 bv = *pb(RW1s, 16, w * 4 + ti, kt, lane);
                a1[ti] = __builtin_amdgcn_mfma_f32_16x16x32_bf16(af, bv, a1[ti], 0, 0, 0);
            }
        }
        // epilogue: q1 -> LDS, and (only now) det <- h  (E1 loads have drained)
        #pragma unroll
        for (int ti = 0; ti < 4; ++ti) {
            const int j = w * 64 + ti * 16 + m16;
            #pragma unroll
            for (int rr = 0; rr < 4; ++rr) {
                q1A[q * 4 + rr][j] = f2bf(eluf(a1[ti][rr]));
                det[((size_t)(b0 + q * 4 + rr) * T_ + t) * DET_ + j] = hprev[ti][rr];
            }
        }
        __syncthreads();   // (2)

        // ---- rep2 GEMM (q1A x RW2p), N=64 on waves 0..3 ----
        if (w < 4) {
            f32x4 a2 = zero4;
            #pragma unroll 2
            for (int kt = 0; kt < 16; ++kt) {
                const int k0 = kt * 32;
                bhalf8 af = *(const bhalf8*)&q1A[m16][k0 + q * 8];
                bhalf8 bv = *pb(RW2p, 16, w, kt, lane);
                a2 = __builtin_amdgcn_mfma_f32_16x16x32_bf16(af, bv, a2, 0, 0, 0);
            }
            #pragma unroll
            for (int rr = 0; rr < 4; ++rr)
                o2[q * 4 + rr][w * 16 + m16] = a2[rr] + rb2g;
        }
        __syncthreads();   // (3)

        // ---- sample: qm/qs/stoch out, s -> gruA, a_{t+1} -> gruA ----
        if (tid < 256) {
            const int row = tid >> 4, c = (tid & 15) * 2;
            float m0 = o2[row][c], m1 = o2[row][c + 1];
            float s0 = softplusf(o2[row][c + 32]) + 0.1f;
            float s1 = softplusf(o2[row][c + 33]) + 0.1f;
            size_t base = ((size_t)(b0 + row) * T_ + t) * STOCH_ + c;
            float2 nz = *(const float2*)&noise[base];
            float st0 = m0 + s0 * nz.x, st1 = m1 + s1 * nz.y;
            *(float2*)&qm[base]    = make_float2(m0, m1);
            *(float2*)&qsd[base]   = make_float2(s0, s1);
            *(float2*)&stoch[base] = make_float2(st0, st1);
            short2 sp; sp.x = f2bf(st0); sp.y = f2bf(st1);
            *(short2*)&gruA[row][c] = sp;
        }
        if (t + 1 < T_ && tid < 96) {
            int row = tid / 6, k = tid - row * 6;
            gruA[row][32 + k] = f2bf(actions[((size_t)(b0 + row) * T_ + (t + 1)) * ACTD_ + k]);
        }
        __syncthreads();   // (4)
    }
}

// ---------------------------------------------------------------------------
// Trans MLP, MFMA, fused 2 layers. M=64/WG, grid 1024, 4 waves split N.
// (unchanged this round; ~0.36 ms — next-round target)
// ---------------------------------------------------------------------------
__global__ __launch_bounds__(256, 2) void k_trans(
    const float* __restrict__ det,
    const float* __restrict__ tw1, const float* __restrict__ tb1,
    const float* __restrict__ tw2, const float* __restrict__ tb2,
    float* __restrict__ pm, float* __restrict__ ps)
{
    __shared__ __align__(16) short buf[64][520];
    const int tid = threadIdx.x;
    const int lane = tid & 63, w = tid >> 6;
    const int q = lane >> 4, m16 = lane & 15;
    const size_t row0 = (size_t)blockIdx.x * 64;

    {
        const int row = tid >> 2, c0 = (tid & 3) * 128;
        const float* src = det + (row0 + row) * 512 + c0;
        #pragma unroll
        for (int v = 0; v < 8; ++v) {
            float4 f0 = ((const float4*)src)[v * 4 + 0];
            float4 f1 = ((const float4*)src)[v * 4 + 1];
            float4 f2 = ((const float4*)src)[v * 4 + 2];
            float4 f3 = ((const float4*)src)[v * 4 + 3];
            short tmp[16] __attribute__((aligned(16)));
            pack4(&tmp[0], f0); pack4(&tmp[4], f1);
            pack4(&tmp[8], f2); pack4(&tmp[12], f3);
            *(bhalf8*)&buf[row][c0 + v * 16]     = *(bhalf8*)&tmp[0];
            *(bhalf8*)&buf[row][c0 + v * 16 + 8] = *(bhalf8*)&tmp[8];
        }
    }
    __syncthreads();

    float tb1g[8];
    #pragma unroll
    for (int ti = 0; ti < 8; ++ti) tb1g[ti] = tb1[w * 128 + ti * 16 + m16];

    f32x4 acc[4][8];
    #pragma unroll
    for (int mt = 0; mt < 4; ++mt)
        #pragma unroll
        for (int ti = 0; ti < 8; ++ti) acc[mt][ti] = (f32x4){0.f, 0.f, 0.f, 0.f};

    #pragma unroll 2
    for (int kt = 0; kt < 16; ++kt) {
        const int k0 = kt * 32;
        bhalf8 af[4];
        #pragma unroll
        for (int mt = 0; mt < 4; ++mt)
            af[mt] = *(const bhalf8*)&buf[mt * 16 + m16][k0 + q * 8];
        #pragma unroll
        for (int ti = 0; ti < 8; ++ti) {
            const int nr = w * 128 + ti * 16 + m16;
            const float* bsrc = tw1 + (size_t)nr * 512 + k0 + q * 8;
            float4 g0 = ((const float4*)bsrc)[0];
            float4 g1 = ((const float4*)bsrc)[1];
            short bt[8] __attribute__((aligned(16)));
            pack4(&bt[0], g0); pack4(&bt[4], g1);
            bhalf8 bv = *(bhalf8*)&bt[0];
            #pragma unroll
            for (int mt = 0; mt < 4; ++mt)
                acc[mt][ti] = __builtin_amdgcn_mfma_f32_16x16x32_bf16(af[mt], bv, acc[mt][ti], 0, 0, 0);
        }
    }
    __syncthreads();
    #pragma unroll
    for (int mt = 0; mt < 4; ++mt)
        #pragma unroll
        for (int ti = 0; ti < 8; ++ti) {
            const int j = w * 128 + ti * 16 + m16;
            #pragma unroll
            for (int rr = 0; rr < 4; ++rr)
                buf[mt * 16 + q * 4 + rr][j] = f2bf(eluf(acc[mt][ti][rr] + tb1g[ti]));
        }
    __syncthreads();

    const float tb2g = tb2[w * 16 + m16];
    f32x4 a2[4];
    #pragma unroll
    for (int mt = 0; mt < 4; ++mt) a2[mt] = (f32x4){0.f, 0.f, 0.f, 0.f};
    #pragma unroll 2
    for (int kt = 0; kt < 16; ++kt) {
        const int k0 = kt * 32;
        const float* bsrc = tw2 + (size_t)(w * 16 + m16) * 512 + k0 + q * 8;
        float4 g0 = ((const float4*)bsrc)[0];
        float4 g1 = ((const float4*)bsrc)[1];
        short bt[8] __attribute__((aligned(16)));
        pack4(&bt[0], g0); pack4(&bt[4], g1);
        bhalf8 bv = *(bhalf8*)&bt[0];
        #pragma unroll
        for (int mt = 0; mt < 4; ++mt) {
            bhalf8 af = *(const bhalf8*)&buf[mt * 16 + m16][k0 + q * 8];
            a2[mt] = __builtin_amdgcn_mfma_f32_16x16x32_bf16(af, bv, a2[mt], 0, 0, 0);
        }
    }
    const int j2 = w * 16 + m16;
    #pragma unroll
    for (int mt = 0; mt < 4; ++mt)
        #pragma unroll
        for (int rr = 0; rr < 4; ++rr) {
            size_t R = row0 + mt * 16 + q * 4 + rr;
            float v = a2[mt][rr] + tb2g;
            if (j2 < 32) pm[R * 32 + j2] = v;
            else         ps[R * 32 + (j2 - 32)] = softplusf(v) + 0.1f;
        }
}

// ---------------------------------------------------------------------------
extern "C" void kernel_launch(void* const* d_in, const int* in_sizes, int n_in,
                              void* d_out, int out_size, void* d_ws, size_t ws_size,
                              hipStream_t stream) {
    const float* emb   = (const float*)d_in[0];
    const float* acts  = (const float*)d_in[1];
    const float* noise = (const float*)d_in[2];
    const float* wih   = (const float*)d_in[3];
    const float* whh   = (const float*)d_in[4];
    const float* bih   = (const float*)d_in[5];
    const float* bhh   = (const float*)d_in[6];
    const float* tw1   = (const float*)d_in[7];
    const float* tb1   = (const float*)d_in[8];
    const float* tw2   = (const float*)d_in[9];
    const float* tb2   = (const float*)d_in[10];
    const float* rw1   = (const float*)d_in[11];
    const float* rb1   = (const float*)d_in[12];
    const float* rw2   = (const float*)d_in[13];
    const float* rb2   = (const float*)d_in[14];

    float* out   = (float*)d_out;
    float* det   = out;
    float* stoch = out + OFF_STOCH;
    float* pm    = out + OFF_PM;
    float* ps    = out + OFF_PS;
    float* qm    = out + OFF_QM;
    float* qsd   = out + OFF_QS;

    // bf16 packed weight scratch in the ps slice; k_trans (the only writer of
    // ps) runs after k_e1/k_scan have fully consumed it.
    // 1,998,848 shorts = 999,424 floats < 2,097,152-float ps slice.
    short* WBIGp = (short*)ps;              // 128*18*512
    short* RW1s  = WBIGp + 128 * 18 * 512;  // 32*16*512
    short* RW1e  = RW1s + 32 * 16 * 512;    // 32*32*512
    short* RW2p  = RW1e + 32 * 32 * 512;    // 4*16*512

    k_prep<<<dim3(1024), 256, 0, stream>>>(wih, whh, rw1, rw2, WBIGp, RW1s, RW1e, RW2p);
    // E1 (e-part of rep1 + rb1) into the det slice; scan reads it as its
    // rep1 accumulator seed, then overwrites det with h.
    k_e1<<<dim3(1024), 256, 0, stream>>>(emb, RW1e, rb1, det);
    k_scan<<<dim3(32), 512, 0, stream>>>(acts, noise, WBIGp, RW1s, RW2p,
                                         bih, bhh, rb2, det, stoch, qm, qsd);
    k_trans<<<dim3(1024), 256, 0, stream>>>(det, tw1, tb1, tw2, tb2, pm, ps);
}

// Round 3
// 4228.296 us; speedup vs baseline: 5.5065x; 1.2535x over previous
//
#include <hip/hip_runtime.h>
#include <hip/hip_bf16.h>
#include <math.h>

#define B_    512
#define T_    128
#define DET_  512
#define STOCH_ 32
#define EMB_  1024
#define ACTD_ 6
#define HID_  512

// output slice offsets (floats)
#define OFF_STOCH 33554432u
#define OFF_PM    35651584u
#define OFF_PS    37748736u
#define OFF_QM    39845888u
#define OFF_QS    41943040u

typedef short bhalf8 __attribute__((ext_vector_type(8)));
typedef float f32x4  __attribute__((ext_vector_type(4)));

__device__ __forceinline__ float sigm(float x) { return 1.f / (1.f + __expf(-x)); }
__device__ __forceinline__ float softplusf(float x) {
    return fmaxf(x, 0.f) + log1pf(__expf(-fabsf(x)));
}
__device__ __forceinline__ float eluf(float x) { return (x > 0.f) ? x : (__expf(x) - 1.f); }
__device__ __forceinline__ float tanh_fast(float x) {
    return 1.f - 2.f / (__expf(2.f * x) + 1.f);
}
__device__ __forceinline__ short f2bf(float f) {
    __hip_bfloat16 h = __float2bfloat16(f);
    return *reinterpret_cast<short*>(&h);
}
__device__ __forceinline__ void pack4(short* dst, float4 f) {
    dst[0] = f2bf(f.x); dst[1] = f2bf(f.y); dst[2] = f2bf(f.z); dst[3] = f2bf(f.w);
}

// Packed-B addressing: weight W[N][K] stored as (N/16)x(K/32) blocks of 512
// shorts; within a block lane L holds W[n = bn*16 + (L&15)][k = bk*32 + (L>>4)*8 + j]
// at short offset L*8+j  ->  a wave's B-fragment load is 1024 CONTIGUOUS bytes.
__device__ __forceinline__ const bhalf8* pb(const short* base, int KT, int bn, int bk, int lane) {
    return (const bhalf8*)(base + ((size_t)((bn * KT + bk) * 64 + lane) << 3));
}

// ---------------------------------------------------------------------------
// Prep: bf16 weight images (fragment-packed) in the ps output slice.
//   WBIGp: N=2048,K=576 (bn 0..127, KT=18). N-rows: 0..511 r [wih_r|whh_r],
//     512..1023 z, 1024..1535 hn [0|whh_n], 1536..2047 xn [wih_n|0].
//     K: k<64 = [s(32),a(6),0(26)], k>=64 = h.
//   RW1s: rep_w1 h-part  N=512,K=512  (KT=16)
//   RW1e: rep_w1 e-part  N=512,K=1024 (KT=32)
//   RW2p: rep_w2         N=64, K=512  (KT=16)
// ---------------------------------------------------------------------------
__global__ __launch_bounds__(256) void k_prep(
    const float* __restrict__ wih, const float* __restrict__ whh,
    const float* __restrict__ rw1, const float* __restrict__ rw2,
    short* __restrict__ WBIGp, short* __restrict__ RW1s,
    short* __restrict__ RW1e, short* __restrict__ RW2p)
{
    const int idx = blockIdx.x * 256 + threadIdx.x;
    const int stride = gridDim.x * 256;

    for (int i = idx; i < 128 * 18 * 512; i += stride) {
        int blk = i >> 9, r = i & 511;
        int lane = r >> 3, j = r & 7;
        int bn = blk / 18, bk = blk - bn * 18;
        int n = bn * 16 + (lane & 15);
        int k = bk * 32 + (lane >> 4) * 8 + j;
        float v = 0.f;
        if (k < 64) {
            if (k < 38) {
                if (n < 1024)       v = wih[n * 38 + k];
                else if (n >= 1536) v = wih[(n - 512) * 38 + k];
            }
        } else {
            if (n < 1536) v = whh[(size_t)n * 512 + (k - 64)];
        }
        WBIGp[i] = f2bf(v);
    }
    for (int i = idx; i < 32 * 16 * 512; i += stride) {
        int blk = i >> 9, r = i & 511;
        int lane = r >> 3, j = r & 7;
        int bn = blk >> 4, bk = blk & 15;
        int n = bn * 16 + (lane & 15), k = bk * 32 + (lane >> 4) * 8 + j;
        RW1s[i] = f2bf(rw1[(size_t)n * 1536 + k]);
    }
    for (int i = idx; i < 32 * 32 * 512; i += stride) {
        int blk = i >> 9, r = i & 511;
        int lane = r >> 3, j = r & 7;
        int bn = blk >> 5, bk = blk & 31;
        int n = bn * 16 + (lane & 15), k = bk * 32 + (lane >> 4) * 8 + j;
        RW1e[i] = f2bf(rw1[(size_t)n * 1536 + 512 + k]);
    }
    for (int i = idx; i < 4 * 16 * 512; i += stride) {
        int blk = i >> 9, r = i & 511;
        int lane = r >> 3, j = r & 7;
        int bn = blk >> 4, bk = blk & 15;
        int n = bn * 16 + (lane & 15), k = bk * 32 + (lane >> 4) * 8 + j;
        RW2p[i] = f2bf(rw2[n * 512 + k]);
    }
}

// ---------------------------------------------------------------------------
// E1 precompute: E1[b,t,:] = emb[b,t,:] @ RW1e^T + rb1   (the scan-independent
// 2/3 of the rep1 K-reduction, + its bias). Stored fp32 into the det slice
// ([b][t][512] layout); k_scan reads E1[b,t] at step t then overwrites with h.
// ---------------------------------------------------------------------------
__global__ __launch_bounds__(256) void k_e1(
    const float* __restrict__ emb, const short* __restrict__ RW1e,
    const float* __restrict__ rb1, float* __restrict__ e1out)
{
    __shared__ __align__(16) short A[64][1032];
    const int tid = threadIdx.x;
    const int lane = tid & 63, w = tid >> 6;
    const int q = lane >> 4, m16 = lane & 15;
    const size_t row0 = (size_t)blockIdx.x * 64;

    {
        const int row = tid >> 2, c0 = (tid & 3) * 256;
        const float* src = emb + (row0 + row) * EMB_ + c0;
        #pragma unroll
        for (int v = 0; v < 16; ++v) {
            float4 f0 = ((const float4*)src)[v * 4 + 0];
            float4 f1 = ((const float4*)src)[v * 4 + 1];
            float4 f2 = ((const float4*)src)[v * 4 + 2];
            float4 f3 = ((const float4*)src)[v * 4 + 3];
            short tmp[16] __attribute__((aligned(16)));
            pack4(&tmp[0], f0); pack4(&tmp[4], f1);
            pack4(&tmp[8], f2); pack4(&tmp[12], f3);
            *(bhalf8*)&A[row][c0 + v * 16]     = *(bhalf8*)&tmp[0];
            *(bhalf8*)&A[row][c0 + v * 16 + 8] = *(bhalf8*)&tmp[8];
        }
    }
    __syncthreads();

    float rb1g[8];
    #pragma unroll
    for (int ti = 0; ti < 8; ++ti) rb1g[ti] = rb1[w * 128 + ti * 16 + m16];

    f32x4 acc[4][8];
    #pragma unroll
    for (int mt = 0; mt < 4; ++mt)
        #pragma unroll
        for (int ti = 0; ti < 8; ++ti) acc[mt][ti] = (f32x4){0.f, 0.f, 0.f, 0.f};

    #pragma unroll 2
    for (int kt = 0; kt < 32; ++kt) {
        const int k0 = kt * 32;
        bhalf8 af[4];
        #pragma unroll
        for (int mt = 0; mt < 4; ++mt)
            af[mt] = *(const bhalf8*)&A[mt * 16 + m16][k0 + q * 8];
        #pragma unroll
        for (int ti = 0; ti < 8; ++ti) {
            bhalf8 bv = *pb(RW1e, 32, w * 8 + ti, kt, lane);
            #pragma unroll
            for (int mt = 0; mt < 4; ++mt)
                acc[mt][ti] = __builtin_amdgcn_mfma_f32_16x16x32_bf16(af[mt], bv, acc[mt][ti], 0, 0, 0);
        }
    }
    #pragma unroll
    for (int mt = 0; mt < 4; ++mt)
        #pragma unroll
        for (int ti = 0; ti < 8; ++ti) {
            const int j = w * 128 + ti * 16 + m16;
            #pragma unroll
            for (int rr = 0; rr < 4; ++rr)
                e1out[(row0 + mt * 16 + q * 4 + rr) * DET_ + j] = acc[mt][ti][rr] + rb1g[ti];
        }
}

// ---------------------------------------------------------------------------
// Persistent scan: 32 WGs x 1024 thr (16 waves -> 4 waves/SIMD). WG owns 16
// batch rows for all 128 steps. Wave w owns N-cols [w*32, w*32+32) of GRU
// gates and rep1. rep2 is K-split: wave (g=w>>2, w4=w&3) computes K-quarter g
// of N-block w4 into o2p; the sample phase reduces the 4 partials (+rb2).
// rep1's A (h) is read directly from gruA cols 64+ (no separate repA buffer).
// ---------------------------------------------------------------------------
__global__ __launch_bounds__(1024, 4) void k_scan(
    const float* __restrict__ actions, const float* __restrict__ noise,
    const short* __restrict__ WBIGp, const short* __restrict__ RW1s,
    const short* __restrict__ RW2p,
    const float* __restrict__ bih, const float* __restrict__ bhh,
    const float* __restrict__ rb2,
    float* __restrict__ det, float* __restrict__ stoch,
    float* __restrict__ qm, float* __restrict__ qsd)
{
    __shared__ __align__(16) short gruA[16][584];   // [s|a|pad|h] bf16
    __shared__ __align__(16) short q1A[16][520];    // q1 bf16
    __shared__ float o2p[4][16][68];                // rep2 K-partials fp32

    const int tid = threadIdx.x;
    const int lane = tid & 63, w = tid >> 6;
    const int q = lane >> 4, m16 = lane & 15;
    const int w4 = w & 3, g = w >> 2;               // rep2 split
    const int b0 = blockIdx.x * 16;
    const f32x4 zero4 = {0.f, 0.f, 0.f, 0.f};

    // ---- prologue ----
    for (int i = tid; i < 16 * 584; i += 1024) ((short*)gruA)[i] = 0;
    if (tid < 96) {
        int row = tid / 6, k = tid - row * 6;
        gruA[row][32 + k] = f2bf(actions[((size_t)(b0 + row) * T_) * ACTD_ + k]);
    }
    float brg[2], bzg[2], bnxg[2], bnhg[2];
    #pragma unroll
    for (int ti = 0; ti < 2; ++ti) {
        int j = w * 32 + ti * 16 + m16;
        brg[ti]  = bih[j] + bhh[j];
        bzg[ti]  = bih[512 + j] + bhh[512 + j];
        bnxg[ti] = bih[1024 + j];
        bnhg[ti] = bhh[1024 + j];
    }
    // rb2 for the sample phase (threads 0..255 only)
    float rb2m0 = 0.f, rb2m1 = 0.f, rb2s0 = 0.f, rb2s1 = 0.f;
    if (tid < 256) {
        const int c = (tid & 15) * 2;
        rb2m0 = rb2[c];      rb2m1 = rb2[c + 1];
        rb2s0 = rb2[c + 32]; rb2s1 = rb2[c + 33];
    }
    float hprev[2][4];
    #pragma unroll
    for (int ti = 0; ti < 2; ++ti)
        #pragma unroll
        for (int rr = 0; rr < 4; ++rr) hprev[ti][rr] = 0.f;
    __syncthreads();

    for (int t = 0; t < T_; ++t) {
        // ---- E1 prefetch: rep1 accumulator seed; latency hides under GRU.
        // Reads det[b][t] before this step's h overwrites it (h stores issue
        // only after rep1's MFMAs have consumed a1).
        f32x4 a1[2];
        #pragma unroll
        for (int ti = 0; ti < 2; ++ti) {
            const int j = w * 32 + ti * 16 + m16;
            #pragma unroll
            for (int rr = 0; rr < 4; ++rr)
                a1[ti][rr] = det[((size_t)(b0 + q * 4 + rr) * T_ + t) * DET_ + j];
        }

        // ---- GRU GEMM (gruA x WBIGp), K=576 ----
        f32x4 aR[2], aZ[2], aN[2], aX[2];
        #pragma unroll
        for (int ti = 0; ti < 2; ++ti) { aR[ti] = zero4; aZ[ti] = zero4; aN[ti] = zero4; aX[ti] = zero4; }

        #pragma unroll 2
        for (int kt = 0; kt < 18; ++kt) {
            const int k0 = kt * 32;
            bhalf8 af = *(const bhalf8*)&gruA[m16][k0 + q * 8];
            #pragma unroll
            for (int ti = 0; ti < 2; ++ti) {
                const int bn = w * 2 + ti;
                bhalf8 bR = *pb(WBIGp, 18, bn, kt, lane);
                bhalf8 bZ = *pb(WBIGp, 18, 32 + bn, kt, lane);
                if (kt < 2) {
                    bhalf8 bX = *pb(WBIGp, 18, 96 + bn, kt, lane);   // xn (x-part)
                    aX[ti] = __builtin_amdgcn_mfma_f32_16x16x32_bf16(af, bX, aX[ti], 0, 0, 0);
                } else {
                    bhalf8 bN = *pb(WBIGp, 18, 64 + bn, kt, lane);   // hn (h-part)
                    aN[ti] = __builtin_amdgcn_mfma_f32_16x16x32_bf16(af, bN, aN[ti], 0, 0, 0);
                }
                aR[ti] = __builtin_amdgcn_mfma_f32_16x16x32_bf16(af, bR, aR[ti], 0, 0, 0);
                aZ[ti] = __builtin_amdgcn_mfma_f32_16x16x32_bf16(af, bZ, aZ[ti], 0, 0, 0);
            }
        }

        // ---- gate epilogue: h into registers ----
        #pragma unroll
        for (int ti = 0; ti < 2; ++ti)
            #pragma unroll
            for (int rr = 0; rr < 4; ++rr) {
                float r = sigm(aR[ti][rr] + brg[ti]);
                float z = sigm(aZ[ti][rr] + bzg[ti]);
                float n = tanh_fast(aX[ti][rr] + bnxg[ti] + r * (aN[ti][rr] + bnhg[ti]));
                hprev[ti][rr] = (1.f - z) * n + z * hprev[ti][rr];
            }
        __syncthreads();   // (1) all GRU reads of gruA h-cols done
        #pragma unroll
        for (int ti = 0; ti < 2; ++ti) {
            const int j = w * 32 + ti * 16 + m16;
            #pragma unroll
            for (int rr = 0; rr < 4; ++rr)
                gruA[q * 4 + rr][64 + j] = f2bf(hprev[ti][rr]);
        }
        __syncthreads();   // (2) h_t complete in gruA

        // ---- rep1 GEMM (gruA h-cols x RW1s), K=512, acc seeded with E1+rb1 ----
        #pragma unroll 2
        for (int kt = 0; kt < 16; ++kt) {
            const int k0 = 64 + kt * 32;
            bhalf8 af = *(const bhalf8*)&gruA[m16][k0 + q * 8];
            #pragma unroll
            for (int ti = 0; ti < 2; ++ti) {
                bhalf8 bv = *pb(RW1s, 16, w * 2 + ti, kt, lane);
                a1[ti] = __builtin_amdgcn_mfma_f32_16x16x32_bf16(af, bv, a1[ti], 0, 0, 0);
            }
        }
        // epilogue: q1 -> LDS, and (only now) det <- h  (E1 loads consumed)
        #pragma unroll
        for (int ti = 0; ti < 2; ++ti) {
            const int j = w * 32 + ti * 16 + m16;
            #pragma unroll
            for (int rr = 0; rr < 4; ++rr) {
                q1A[q * 4 + rr][j] = f2bf(eluf(a1[ti][rr]));
                det[((size_t)(b0 + q * 4 + rr) * T_ + t) * DET_ + j] = hprev[ti][rr];
            }
        }
        __syncthreads();   // (3)

        // ---- rep2 GEMM (q1A x RW2p), K-split: wave (g,w4) does kt g*4..g*4+3 ----
        {
            f32x4 a2 = zero4;
            #pragma unroll
            for (int i = 0; i < 4; ++i) {
                const int kt = g * 4 + i;
                const int k0 = kt * 32;
                bhalf8 af = *(const bhalf8*)&q1A[m16][k0 + q * 8];
                bhalf8 bv = *pb(RW2p, 16, w4, kt, lane);
                a2 = __builtin_amdgcn_mfma_f32_16x16x32_bf16(af, bv, a2, 0, 0, 0);
            }
            #pragma unroll
            for (int rr = 0; rr < 4; ++rr)
                o2p[g][q * 4 + rr][w4 * 16 + m16] = a2[rr];
        }
        __syncthreads();   // (4)

        // ---- sample: reduce K-partials, qm/qs/stoch out, s -> gruA ----
        if (tid < 256) {
            const int row = tid >> 4, c = (tid & 15) * 2;
            float m0 = o2p[0][row][c]      + o2p[1][row][c]      + o2p[2][row][c]      + o2p[3][row][c]      + rb2m0;
            float m1 = o2p[0][row][c + 1]  + o2p[1][row][c + 1]  + o2p[2][row][c + 1]  + o2p[3][row][c + 1]  + rb2m1;
            float v0 = o2p[0][row][c + 32] + o2p[1][row][c + 32] + o2p[2][row][c + 32] + o2p[3][row][c + 32] + rb2s0;
            float v1 = o2p[0][row][c + 33] + o2p[1][row][c + 33] + o2p[2][row][c + 33] + o2p[3][row][c + 33] + rb2s1;
            float s0 = softplusf(v0) + 0.1f;
            float s1 = softplusf(v1) + 0.1f;
            size_t base = ((size_t)(b0 + row) * T_ + t) * STOCH_ + c;
            float2 nz = *(const float2*)&noise[base];
            float st0 = m0 + s0 * nz.x, st1 = m1 + s1 * nz.y;
            *(float2*)&qm[base]    = make_float2(m0, m1);
            *(float2*)&qsd[base]   = make_float2(s0, s1);
            *(float2*)&stoch[base] = make_float2(st0, st1);
            short2 sp; sp.x = f2bf(st0); sp.y = f2bf(st1);
            *(short2*)&gruA[row][c] = sp;
        }
        if (t + 1 < T_ && tid < 96) {
            int row = tid / 6, k = tid - row * 6;
            gruA[row][32 + k] = f2bf(actions[((size_t)(b0 + row) * T_ + (t + 1)) * ACTD_ + k]);
        }
        __syncthreads();   // (5)
    }
}

// ---------------------------------------------------------------------------
// Trans MLP, MFMA, fused 2 layers. M=64/WG, grid 1024, 4 waves split N.
// ---------------------------------------------------------------------------
__global__ __launch_bounds__(256, 2) void k_trans(
    const float* __restrict__ det,
    const float* __restrict__ tw1, const float* __restrict__ tb1,
    const float* __restrict__ tw2, const float* __restrict__ tb2,
    float* __restrict__ pm, float* __restrict__ ps)
{
    __shared__ __align__(16) short buf[64][520];
    const int tid = threadIdx.x;
    const int lane = tid & 63, w = tid >> 6;
    const int q = lane >> 4, m16 = lane & 15;
    const size_t row0 = (size_t)blockIdx.x * 64;

    {
        const int row = tid >> 2, c0 = (tid & 3) * 128;
        const float* src = det + (row0 + row) * 512 + c0;
        #pragma unroll
        for (int v = 0; v < 8; ++v) {
            float4 f0 = ((const float4*)src)[v * 4 + 0];
            float4 f1 = ((const float4*)src)[v * 4 + 1];
            float4 f2 = ((const float4*)src)[v * 4 + 2];
            float4 f3 = ((const float4*)src)[v * 4 + 3];
            short tmp[16] __attribute__((aligned(16)));
            pack4(&tmp[0], f0); pack4(&tmp[4], f1);
            pack4(&tmp[8], f2); pack4(&tmp[12], f3);
            *(bhalf8*)&buf[row][c0 + v * 16]     = *(bhalf8*)&tmp[0];
            *(bhalf8*)&buf[row][c0 + v * 16 + 8] = *(bhalf8*)&tmp[8];
        }
    }
    __syncthreads();

    float tb1g[8];
    #pragma unroll
    for (int ti = 0; ti < 8; ++ti) tb1g[ti] = tb1[w * 128 + ti * 16 + m16];

    f32x4 acc[4][8];
    #pragma unroll
    for (int mt = 0; mt < 4; ++mt)
        #pragma unroll
        for (int ti = 0; ti < 8; ++ti) acc[mt][ti] = (f32x4){0.f, 0.f, 0.f, 0.f};

    #pragma unroll 2
    for (int kt = 0; kt < 16; ++kt) {
        const int k0 = kt * 32;
        bhalf8 af[4];
        #pragma unroll
        for (int mt = 0; mt < 4; ++mt)
            af[mt] = *(const bhalf8*)&buf[mt * 16 + m16][k0 + q * 8];
        #pragma unroll
        for (int ti = 0; ti < 8; ++ti) {
            const int nr = w * 128 + ti * 16 + m16;
            const float* bsrc = tw1 + (size_t)nr * 512 + k0 + q * 8;
            float4 g0 = ((const float4*)bsrc)[0];
            float4 g1 = ((const float4*)bsrc)[1];
            short bt[8] __attribute__((aligned(16)));
            pack4(&bt[0], g0); pack4(&bt[4], g1);
            bhalf8 bv = *(bhalf8*)&bt[0];
            #pragma unroll
            for (int mt = 0; mt < 4; ++mt)
                acc[mt][ti] = __builtin_amdgcn_mfma_f32_16x16x32_bf16(af[mt], bv, acc[mt][ti], 0, 0, 0);
        }
    }
    __syncthreads();
    #pragma unroll
    for (int mt = 0; mt < 4; ++mt)
        #pragma unroll
        for (int ti = 0; ti < 8; ++ti) {
            const int j = w * 128 + ti * 16 + m16;
            #pragma unroll
            for (int rr = 0; rr < 4; ++rr)
                buf[mt * 16 + q * 4 + rr][j] = f2bf(eluf(acc[mt][ti][rr] + tb1g[ti]));
        }
    __syncthreads();

    const float tb2g = tb2[w * 16 + m16];
    f32x4 a2[4];
    #pragma unroll
    for (int mt = 0; mt < 4; ++mt) a2[mt] = (f32x4){0.f, 0.f, 0.f, 0.f};
    #pragma unroll 2
    for (int kt = 0; kt < 16; ++kt) {
        const int k0 = kt * 32;
        const float* bsrc = tw2 + (size_t)(w * 16 + m16) * 512 + k0 + q * 8;
        float4 g0 = ((const float4*)bsrc)[0];
        float4 g1 = ((const float4*)bsrc)[1];
        short bt[8] __attribute__((aligned(16)));
        pack4(&bt[0], g0); pack4(&bt[4], g1);
        bhalf8 bv = *(bhalf8*)&bt[0];
        #pragma unroll
        for (int mt = 0; mt < 4; ++mt) {
            bhalf8 af = *(const bhalf8*)&buf[mt * 16 + m16][k0 + q * 8];
            a2[mt] = __builtin_amdgcn_mfma_f32_16x16x32_bf16(af, bv, a2[mt], 0, 0, 0);
        }
    }
    const int j2 = w * 16 + m16;
    #pragma unroll
    for (int mt = 0; mt < 4; ++mt)
        #pragma unroll
        for (int rr = 0; rr < 4; ++rr) {
            size_t R = row0 + mt * 16 + q * 4 + rr;
            float v = a2[mt][rr] + tb2g;
            if (j2 < 32) pm[R * 32 + j2] = v;
            else         ps[R * 32 + (j2 - 32)] = softplusf(v) + 0.1f;
        }
}

// ---------------------------------------------------------------------------
extern "C" void kernel_launch(void* const* d_in, const int* in_sizes, int n_in,
                              void* d_out, int out_size, void* d_ws, size_t ws_size,
                              hipStream_t stream) {
    const float* emb   = (const float*)d_in[0];
    const float* acts  = (const float*)d_in[1];
    const float* noise = (const float*)d_in[2];
    const float* wih   = (const float*)d_in[3];
    const float* whh   = (const float*)d_in[4];
    const float* bih   = (const float*)d_in[5];
    const float* bhh   = (const float*)d_in[6];
    const float* tw1   = (const float*)d_in[7];
    const float* tb1   = (const float*)d_in[8];
    const float* tw2   = (const float*)d_in[9];
    const float* tb2   = (const float*)d_in[10];
    const float* rw1   = (const float*)d_in[11];
    const float* rb1   = (const float*)d_in[12];
    const float* rw2   = (const float*)d_in[13];
    const float* rb2   = (const float*)d_in[14];

    float* out   = (float*)d_out;
    float* det   = out;
    float* stoch = out + OFF_STOCH;
    float* pm    = out + OFF_PM;
    float* ps    = out + OFF_PS;
    float* qm    = out + OFF_QM;
    float* qsd   = out + OFF_QS;

    // bf16 packed weight scratch in the ps slice; k_trans (the only writer of
    // ps) runs after k_e1/k_scan have fully consumed it.
    short* WBIGp = (short*)ps;              // 128*18*512
    short* RW1s  = WBIGp + 128 * 18 * 512;  // 32*16*512
    short* RW1e  = RW1s + 32 * 16 * 512;    // 32*32*512
    short* RW2p  = RW1e + 32 * 32 * 512;    // 4*16*512

    k_prep<<<dim3(1024), 256, 0, stream>>>(wih, whh, rw1, rw2, WBIGp, RW1s, RW1e, RW2p);
    k_e1<<<dim3(1024), 256, 0, stream>>>(emb, RW1e, rb1, det);
    k_scan<<<dim3(32), 1024, 0, stream>>>(acts, noise, WBIGp, RW1s, RW2p,
                                          bih, bhh, rb2, det, stoch, qm, qsd);
    k_trans<<<dim3(1024), 256, 0, stream>>>(det, tw1, tb1, tw2, tb2, pm, ps);
}